// Round 2
// baseline (958.968 us; speedup 1.0000x reference)
//
#include <hip/hip_runtime.h>

static constexpr int INN  = 4096;
static constexpr int HID  = 8192;
static constexpr int OUTN = 2048;
static constexpr float LR  = 0.01f;
static constexpr float B1  = 0.9f;
static constexpr float B2  = 0.999f;
static constexpr float EPS = 1e-8f;

// workspace layout (float offsets) — total 92160 floats = 360 KB
static constexpr int PH    = 0;                 // [HID]      b_h + rho(x)@W1
static constexpr int WPART = PH + HID;          // [16][OUTN] w chunk-partials
static constexpr int RHOH  = WPART + 16 * OUTN; // [2][HID]   rho(h) double buf
static constexpr int RHOO  = RHOH + 2 * HID;    // [2][OUTN]  rho(o) double buf
static constexpr int HS    = RHOO + 2 * OUTN;   // [3][HID]   h, m_h, v_h
static constexpr int OS    = HS + 3 * HID;      // [3][OUTN]  o, m_o, v_o
static constexpr int WSEND = OS + 3 * OUTN;     // 92160
static constexpr int ZBASE = RHOH;              // zero region RHOH..WSEND
static constexpr int ZLEN  = WSEND - ZBASE;     // 51200

__device__ __forceinline__ float rho01(float v) { return fminf(fmaxf(v, 0.f), 1.f); }

// ---------------- setup: ph = b_h + rho(x)@W1 ; zero state/rho buffers ----------------
__global__ void __launch_bounds__(256)
k_setup(const float* __restrict__ x, const float* __restrict__ W1,
        const float* __restrict__ b_h, float* __restrict__ ws)
{
    const int t = threadIdx.x, b = blockIdx.x;
    if (b < 256) {
        __shared__ float rx[INN];     // 16 KB: rho(x) staged once
        __shared__ float red[256];
        #pragma unroll
        for (int k = 0; k < INN / 256; ++k) rx[k * 256 + t] = rho01(x[k * 256 + t]);
        __syncthreads();
        const int j  = b * 32 + (t & 31);   // column of W1
        const int r0 = t >> 5;              // row offset 0..7
        float acc = 0.f;
        #pragma unroll 8
        for (int k = 0; k < 512; ++k) {
            const int i = r0 + 8 * k;
            acc = fmaf(rx[i], W1[(size_t)i * HID + j], acc);
        }
        red[t] = acc;
        __syncthreads();
        if (t < 32) {
            float s = 0.f;
            #pragma unroll
            for (int q = 0; q < 8; ++q) s += red[q * 32 + t];
            const int jj = b * 32 + t;
            ws[PH + jj] = s + b_h[jj];
        }
    } else {
        const int zb = b - 256;            // 0..7
        float* z = ws + ZBASE;
        #pragma unroll
        for (int k = 0; k < 25; ++k) {
            const int idx = zb * 6400 + k * 256 + t;
            if (idx < ZLEN) z[idx] = 0.f;
        }
    }
}

// ---------------- K_w: chunk-partials of w = rho(h) @ W2 (column matvec) ----------------
// 512 blocks: b&31 = column group (64 cols), b>>5 = row chunk (512 rows)
__global__ void __launch_bounds__(256)
k_w(const float* __restrict__ W2, float* __restrict__ ws,
    const int* __restrict__ nit, int t_iter)
{
    if (nit[0] < t_iter) return;
    const int t = threadIdx.x, b = blockIdx.x;
    const int cg = b & 31, rc = b >> 5;
    const int j  = cg * 64 + (t & 63);
    const int i0 = rc * 512;
    const float* rhoH = ws + RHOH + ((t_iter - 1) & 1) * HID;

    __shared__ float rh[512];
    __shared__ float red[256];
    rh[t]       = rhoH[i0 + t];
    rh[256 + t] = rhoH[i0 + 256 + t];
    __syncthreads();

    const int ro = t >> 6;   // row offset 0..3
    float acc = 0.f;
    #pragma unroll 8
    for (int k = 0; k < 128; ++k) {
        const int i = ro + 4 * k;
        acc = fmaf(rh[i], W2[(size_t)(i0 + i) * OUTN + j], acc);
    }
    red[t] = acc;
    __syncthreads();
    if (t < 64) {
        const float s = red[t] + red[t + 64] + red[t + 128] + red[t + 192];
        ws[WPART + rc * OUTN + cg * 64 + t] = s;
    }
}

// ---------------- K_uo: u = W2 @ rho(o) + h-Adam (512 blocks) ; w-reduce + o-Adam (4 blocks) ----
__global__ void __launch_bounds__(256)
k_uo(const float* __restrict__ W2, const float* __restrict__ b_o,
     float* __restrict__ ws, float* __restrict__ out,
     const int* __restrict__ nit, int t_iter, float ub1, float ub2)
{
    if (nit[0] < t_iter) return;
    const int t = threadIdx.x, b = blockIdx.x;
    const int oldp = (t_iter - 1) & 1, newp = t_iter & 1;

    if (b < 512) {
        // ---- u-phase: rows i0..i0+15, 4 rows per wave, float4 dots ----
        const int lane = t & 63, wv = t >> 6;
        const int i0 = b * 16 + wv * 4;
        const float4* ro4 = reinterpret_cast<const float4*>(ws + RHOO + oldp * OUTN);

        float4 rv[8];
        #pragma unroll
        for (int k = 0; k < 8; ++k) rv[k] = ro4[lane + 64 * k];

        float acc[4];
        #pragma unroll
        for (int r = 0; r < 4; ++r) {
            const float4* w4 = reinterpret_cast<const float4*>(W2 + (size_t)(i0 + r) * OUTN);
            float4 s4 = make_float4(0.f, 0.f, 0.f, 0.f);
            #pragma unroll
            for (int k = 0; k < 8; ++k) {
                const float4 a = w4[lane + 64 * k];
                s4.x = fmaf(a.x, rv[k].x, s4.x);
                s4.y = fmaf(a.y, rv[k].y, s4.y);
                s4.z = fmaf(a.z, rv[k].z, s4.z);
                s4.w = fmaf(a.w, rv[k].w, s4.w);
            }
            acc[r] = (s4.x + s4.y) + (s4.z + s4.w);
        }
        #pragma unroll
        for (int r = 0; r < 4; ++r)
            #pragma unroll
            for (int off = 1; off < 64; off <<= 1) acc[r] += __shfl_xor(acc[r], off, 64);

        float* hv  = ws + HS;
        float* hm  = ws + HS + HID;
        float* hvv = ws + HS + 2 * HID;
        const float* ph = ws + PH;
        float* rhoHn = ws + RHOH + newp * HID;
        #pragma unroll
        for (int r = 0; r < 4; ++r) {
            const int i = i0 + r;
            float h = hv[i], m = hm[i], v = hvv[i];
            const float mask = (h >= 0.f && h <= 1.f) ? 1.f : 0.f;
            const float g = h - mask * (ph[i] + acc[r]);
            m = B1 * m + (1.f - B1) * g;
            v = B2 * v + (1.f - B2) * g * g;
            h -= LR * (m * ub1) / (sqrtf(v * ub2) + EPS);
            if (lane == 0) { hv[i] = h; hm[i] = m; hvv[i] = v; rhoHn[i] = rho01(h); }
        }
    } else {
        // ---- o-phase: reduce w partials, o-Adam, write rho(o) and out ----
        const int ob = b - 512;   // 0..3, 512 cols each
        float* ov  = ws + OS;
        float* om  = ws + OS + OUTN;
        float* ovv = ws + OS + 2 * OUTN;
        float* rhoOn = ws + RHOO + newp * OUTN;
        #pragma unroll
        for (int q = 0; q < 2; ++q) {
            const int j = ob * 512 + q * 256 + t;
            float s = 0.f;
            #pragma unroll
            for (int c = 0; c < 16; ++c) s += ws[WPART + c * OUTN + j];
            float o = ov[j], m = om[j], v = ovv[j];
            const float mask = (o >= 0.f && o <= 1.f) ? 1.f : 0.f;
            const float g = o - mask * (b_o[j] + s);
            m = B1 * m + (1.f - B1) * g;
            v = B2 * v + (1.f - B2) * g * g;
            o -= LR * (m * ub1) / (sqrtf(v * ub2) + EPS);
            ov[j] = o; om[j] = m; ovv[j] = v;
            rhoOn[j] = rho01(o);
            out[j] = o;
        }
    }
}

extern "C" void kernel_launch(void* const* d_in, const int* in_sizes, int n_in,
                              void* d_out, int out_size, void* d_ws, size_t ws_size,
                              hipStream_t stream) {
    const float* x  = (const float*)d_in[0];
    const float* W1 = (const float*)d_in[1];
    const float* W2 = (const float*)d_in[2];
    const float* bh = (const float*)d_in[3];
    const float* bo = (const float*)d_in[4];
    const int*  nit = (const int*)d_in[5];
    float* out = (float*)d_out;
    float* ws  = (float*)d_ws;

    k_setup<<<264, 256, 0, stream>>>(x, W1, bh, ws);

    double p1 = 1.0, p2 = 1.0;
    for (int t = 1; t <= 30; ++t) {
        p1 *= (double)B1;
        p2 *= (double)B2;
        const float ub1 = (float)(1.0 / (1.0 - p1));
        const float ub2 = (float)(1.0 / (1.0 - p2));
        k_w <<<512, 256, 0, stream>>>(W2, ws, nit, t);
        k_uo<<<516, 256, 0, stream>>>(W2, bo, ws, out, nit, t, ub1, ub2);
    }
}